// Round 9
// baseline (297.342 us; speedup 1.0000x reference)
//
#include <hip/hip_runtime.h>

#define N_NODES 50000
#define N_EDGES 800000
#define FEATS 128
#define NCHUNK 196            // ceil(50000/256)
#define CPAD 50176            // NCHUNK*256 (counts/offsets padded, zeroed)
#define GEMM_QV 392           // q+v blocks, 2 tiles each (A shared across q and v)
#define GEMM_K 196            // k blocks, 4 tiles each
#define GEMM_BLOCKS 588
#define SCAT_BLOCKS 3125      // 3125*256 = 800000 exactly
#define NTILE 782             // ceil(50000/64)
#define NF_WAVES 8192

typedef __attribute__((ext_vector_type(8))) short bf16x8;
typedef __attribute__((ext_vector_type(4))) float f32x4;

__device__ __forceinline__ unsigned short f2bf(float f){
  unsigned u = __float_as_uint(f);
  u += 0x7FFF + ((u >> 16) & 1);           // RNE
  return (unsigned short)(u >> 16);
}
// bf16 pair unpack, 1 VALU op per float
__device__ __forceinline__ void unpack8(uint4 p, float* f){
  f[0]=__uint_as_float(p.x << 16); f[1]=__uint_as_float(p.x & 0xffff0000u);
  f[2]=__uint_as_float(p.y << 16); f[3]=__uint_as_float(p.y & 0xffff0000u);
  f[4]=__uint_as_float(p.z << 16); f[5]=__uint_as_float(p.z & 0xffff0000u);
  f[6]=__uint_as_float(p.w << 16); f[7]=__uint_as_float(p.w & 0xffff0000u);
}

// ---------------- dispatch 1: BN stats (blocks 0..767) || dst hist + chunk sums (768..1023)
__global__ __launch_bounds__(256) void stats_hist_kernel(
    const float* __restrict__ ftq, const float* __restrict__ ftk,
    float* __restrict__ sums, const int* __restrict__ dstE,
    int* __restrict__ counts, int* __restrict__ csums){
  __shared__ float red[4*FEATS];
  __shared__ int lchunk[NCHUNK];
  int tid = threadIdx.x, bid = blockIdx.x;
  if (bid < 768){
    for (int i = tid; i < 4*FEATS; i += 256) red[i] = 0.f;
    __syncthreads();
    int c = tid & 127, half = tid >> 7;
    float sq=0.f, qq=0.f, sk=0.f, kk2=0.f;
    for (int r = bid*2 + half; r < N_NODES; r += 1536){
      float xq = ftq[(size_t)r*FEATS + c];
      float xk = ftk[(size_t)r*FEATS + c];
      sq += xq; qq += xq*xq; sk += xk; kk2 += xk*xk;
    }
    atomicAdd(&red[0*FEATS+c], sq);
    atomicAdd(&red[1*FEATS+c], qq);
    atomicAdd(&red[2*FEATS+c], sk);
    atomicAdd(&red[3*FEATS+c], kk2);
    __syncthreads();
    if (tid < FEATS){
      atomicAdd(&sums[0*FEATS+tid], red[0*FEATS+tid]);
      atomicAdd(&sums[1*FEATS+tid], red[1*FEATS+tid]);
      atomicAdd(&sums[2*FEATS+tid], red[2*FEATS+tid]);
      atomicAdd(&sums[3*FEATS+tid], red[3*FEATS+tid]);
    }
  } else {
    for (int i = tid; i < NCHUNK; i += 256) lchunk[i] = 0;
    __syncthreads();
    for (int t = (bid-768)*256 + tid; t < N_EDGES; t += 256*256){
      int d = dstE[t];
      atomicAdd(&counts[d], 1);
      atomicAdd(&lchunk[d >> 8], 1);
    }
    __syncthreads();
    for (int i = tid; i < NCHUNK; i += 256)
      if (lchunk[i]) atomicAdd(&csums[i], lchunk[i]);
  }
}

// ---------------- dispatch 2: global-offset chunk scans (0..195) || BN-fold (196..291)
// each scan block sums csums[0..bid) itself -> writes GLOBAL offsets directly.
__global__ __launch_bounds__(256) void scan_fold_kernel(
    const int* __restrict__ counts, const int* __restrict__ csums,
    int* __restrict__ offsets,
    const float* __restrict__ Wq, const float* __restrict__ bq,
    const float* __restrict__ Wk, const float* __restrict__ Wv,
    const float* __restrict__ gq, const float* __restrict__ bqn,
    const float* __restrict__ gk, const float* __restrict__ bkn,
    const float* __restrict__ sums,
    unsigned short* __restrict__ Wb, float* __restrict__ bias){
  __shared__ int s[256];
  __shared__ int sbase;
  int tid = threadIdx.x, bid = blockIdx.x;
  if (bid < NCHUNK){
    // 1) chunk base = sum of csums[0..bid)
    s[tid] = (tid < bid) ? csums[tid] : 0;
    __syncthreads();
    for (int d = 128; d > 0; d >>= 1){
      if (tid < d) s[tid] += s[tid + d];
      __syncthreads();
    }
    if (tid == 0) sbase = s[0];
    __syncthreads();
    int base = sbase;
    __syncthreads();
    // 2) chunk-local Hillis-Steele scan
    int i = bid*256 + tid;
    int v = counts[i];                          // padded region is zero
    s[tid] = v; __syncthreads();
    for (int d = 1; d < 256; d <<= 1){
      int tv = (tid >= d) ? s[tid-d] : 0; __syncthreads();
      s[tid] += tv; __syncthreads();
    }
    offsets[i] = base + s[tid] - v;             // global exclusive offsets
  } else {
    int wv = (bid - NCHUNK)*4 + (tid >> 6);     // 0..383
    int lane = tid & 63;
    int m = wv >> 7;                            // 0=q,1=v,2=k
    int o = wv & 127;
    const float* Wsrc = (m==0) ? Wq : (m==1) ? Wv : Wk;
    const float* g   = (m==2) ? gk : gq;
    const float* bb  = (m==2) ? bkn : bqn;
    const float* s0  = (m==2) ? (sums + 2*FEATS) : sums;
    const float invN = 1.0f / (float)N_NODES;
    float acc = 0.f;
    unsigned short w2[2];
    int i0 = lane*2;
    #pragma unroll
    for (int t = 0; t < 2; t++){
      int i = i0 + t;
      float mean = s0[i]*invN;
      float var  = s0[FEATS+i]*invN - mean*mean;
      float rstd = rsqrtf(var + 1e-5f);
      float scale = g[i]*rstd;
      float shift = bb[i] - mean*scale;
      float w = Wsrc[o*FEATS + i];
      w2[t] = f2bf(w*scale);
      acc += shift*w;
    }
    ((unsigned*)Wb)[(m*FEATS*FEATS + o*FEATS + i0) >> 1] =
        (unsigned)w2[0] | ((unsigned)w2[1] << 16);
    #pragma unroll
    for (int off = 1; off < 64; off <<= 1) acc += __shfl_xor(acc, off);
    if (lane == 0) bias[m*FEATS + o] = acc + ((m==0) ? bq[o] : 0.f);
  }
}

// ---------------- dispatch 3: GEMM (0..587) || CSR scatter (588..3712)
// q+v blocks (0..391): 2 tiles of A held in regs across TWO B-passes (Wq',Wv').
// k blocks (392..587): 4 tiles, single B-pass.
__global__ __launch_bounds__(256) void gemm_scatter_kernel(
    const float* __restrict__ ftq, const float* __restrict__ ftk,
    const unsigned short* __restrict__ Wball, const float* __restrict__ biasall,
    unsigned short* __restrict__ qv, unsigned short* __restrict__ kb,
    const int* __restrict__ dstE, const int* __restrict__ srcE,
    const int* __restrict__ offsets, int* __restrict__ cursor,
    int* __restrict__ src_csr){
  __shared__ unsigned short Bs[FEATS][136];
  int tid = threadIdx.x, bid = blockIdx.x;
  if (bid >= GEMM_BLOCKS){
    int t = (bid - GEMM_BLOCKS)*256 + tid;      // exactly covers N_EDGES
    int d = dstE[t];
    int p = atomicAdd(&cursor[d], 1);
    src_csr[offsets[d] + p] = srcE[t];
    return;
  }
  int wave = tid >> 6, lane = tid & 63;
  int mrow = lane & 15, quad = lane >> 4;

  auto loadA = [&](int t, bf16x8* af){
    int row0 = t*64;
    int arow = row0 + wave*16 + mrow;
    bool rok = arow < N_NODES;                  // t >= NTILE -> all rows invalid -> zeros
    const float* X = (bid < GEMM_QV) ? ftq : ftk;
    size_t abase = (size_t)(rok ? arow : 0) * FEATS;
    #pragma unroll
    for (int kt = 0; kt < 4; kt++){
      const float* xp = X + abase + kt*32 + quad*8;
      float4 x0 = *(const float4*)xp;
      float4 x1 = *(const float4*)(xp + 4);
      if (!rok){ x0 = make_float4(0.f,0.f,0.f,0.f); x1 = x0; }
      bf16x8 a;
      a[0]=(short)f2bf(x0.x); a[1]=(short)f2bf(x0.y); a[2]=(short)f2bf(x0.z); a[3]=(short)f2bf(x0.w);
      a[4]=(short)f2bf(x1.x); a[5]=(short)f2bf(x1.y); a[6]=(short)f2bf(x1.z); a[7]=(short)f2bf(x1.w);
      af[kt] = a;
    }
  };
  auto stageB = [&](int m){
    const uint4* srcp = (const uint4*)(Wball + m*FEATS*FEATS);
    for (int idx = tid; idx < FEATS*FEATS/8; idx += 256){
      int n = idx >> 4;
      int kk = (idx & 15) * 8;
      *(uint4*)&Bs[n][kk] = srcp[idx];
    }
  };
  auto compute_store = [&](int t, const bf16x8* af, int m){
    f32x4 acc[8];
    #pragma unroll
    for (int i = 0; i < 8; i++) acc[i] = (f32x4){0.f,0.f,0.f,0.f};
    #pragma unroll
    for (int kt = 0; kt < 4; kt++){
      int kbk = kt*32 + quad*8;
      #pragma unroll
      for (int ct = 0; ct < 8; ct++){
        bf16x8 b = *(bf16x8*)&Bs[ct*16 + mrow][kbk];
        acc[ct] = __builtin_amdgcn_mfma_f32_16x16x32_bf16(af[kt], b, acc[ct], 0, 0, 0);
      }
    }
    unsigned short* Out = (m==2) ? kb : (qv + m*128);
    const int ostride = (m==2) ? FEATS : 256;
    int row0 = t*64;
    #pragma unroll
    for (int ct = 0; ct < 8; ct++){
      int col = ct*16 + mrow;
      float bv = biasall[m*FEATS + col];
      #pragma unroll
      for (int v = 0; v < 4; v++){
        int orow = row0 + wave*16 + quad*4 + v;
        unsigned ub = f2bf(acc[ct][v] + bv);
        unsigned partner = (unsigned)__shfl_xor((int)ub, 1);
        if (!(mrow & 1) && orow < N_NODES)
          *(unsigned*)&Out[(size_t)orow*ostride + col] = ub | (partner << 16);
      }
    }
  };

  if (bid < GEMM_QV){
    int t0 = bid, t1 = bid + GEMM_QV;           // t1 may be >= NTILE (harmless: zero rows)
    bf16x8 a0[4], a1[4];
    stageB(0);
    loadA(t0, a0); loadA(t1, a1);
    __syncthreads();
    compute_store(t0, a0, 0);
    compute_store(t1, a1, 0);
    __syncthreads();
    stageB(1);
    __syncthreads();
    compute_store(t0, a0, 1);
    compute_store(t1, a1, 1);
  } else {
    int bx = bid - GEMM_QV;
    stageB(2);
    __syncthreads();
    bf16x8 af[4];
    for (int t = bx; t < NTILE; t += GEMM_K){
      loadA(t, af);
      compute_store(t, af, 2);
    }
  }
}

// ---------------- dispatch 4: per-dst-node scores + max-free softmax agg (8192 waves)
// 2x edge unroll: 8 independent 16B gathers in flight per iteration.
__global__ __launch_bounds__(256) void node_fused_kernel(
    const unsigned short* __restrict__ qv, const unsigned short* __restrict__ kb,
    const float* __restrict__ attn, const int* __restrict__ src_csr,
    const int* __restrict__ offsets, float* __restrict__ out){
  int tid = threadIdx.x;
  int lane = tid & 63;
  int h = lane & 7, g = lane >> 3;
  int w = blockIdx.x*4 + (tid >> 6);
  const float L2E = 1.44269504f;
  float ar[16];
  {
    const uint4* ap = (const uint4*)(attn + h*16);
    uint4 a0 = ap[0], a1 = ap[1], a2 = ap[2], a3 = ap[3];
    ar[0]=__uint_as_float(a0.x); ar[1]=__uint_as_float(a0.y); ar[2]=__uint_as_float(a0.z); ar[3]=__uint_as_float(a0.w);
    ar[4]=__uint_as_float(a1.x); ar[5]=__uint_as_float(a1.y); ar[6]=__uint_as_float(a1.z); ar[7]=__uint_as_float(a1.w);
    ar[8]=__uint_as_float(a2.x); ar[9]=__uint_as_float(a2.y); ar[10]=__uint_as_float(a2.z); ar[11]=__uint_as_float(a2.w);
    ar[12]=__uint_as_float(a3.x); ar[13]=__uint_as_float(a3.y); ar[14]=__uint_as_float(a3.z); ar[15]=__uint_as_float(a3.w);
  }
  for (int n = w; n < N_NODES; n += NF_WAVES){
    int off0 = offsets[n];
    int deg = offsets[n+1] - off0;
    if (deg == 0){
      ((float2*)(out + (size_t)n*FEATS))[lane] = make_float2(0.f, 0.f);
      continue;
    }
    float kf2[16];
    {
      const unsigned short* kr = kb + (size_t)n*FEATS + h*16;
      uint4 k0 = *(const uint4*)kr;
      uint4 k1 = *(const uint4*)(kr + 8);
      float kf[16]; unpack8(k0, kf); unpack8(k1, kf+8);
      #pragma unroll
      for (int i = 0; i < 16; i++) kf2[i] = -L2E * kf[i];
    }
    float ssum = 0.f;
    float acc[16];
    #pragma unroll
    for (int i = 0; i < 16; i++) acc[i] = 0.f;
    for (int j = g; j < deg; j += 16){
      int j2 = j + 8;
      bool has2 = j2 < deg;
      int s1 = src_csr[off0 + j];
      int s2 = has2 ? src_csr[off0 + j2] : s1;
      const unsigned short* qr1 = qv + (size_t)s1*256 + h*16;
      const unsigned short* qr2 = qv + (size_t)s2*256 + h*16;
      uint4 q10 = *(const uint4*)qr1;
      uint4 q11 = *(const uint4*)(qr1 + 8);
      uint4 v10 = *(const uint4*)(qr1 + 128);
      uint4 v11 = *(const uint4*)(qr1 + 136);
      uint4 q20 = *(const uint4*)qr2;
      uint4 q21 = *(const uint4*)(qr2 + 8);
      uint4 v20 = *(const uint4*)(qr2 + 128);
      uint4 v21 = *(const uint4*)(qr2 + 136);
      float qf[16]; unpack8(q10, qf); unpack8(q11, qf+8);
      float t1 = 0.f;
      #pragma unroll
      for (int i = 0; i < 16; i++){
        float xs = fmaf(qf[i], -L2E, kf2[i]);
        float sg = __builtin_amdgcn_rcpf(1.f + __builtin_amdgcn_exp2f(xs));
        t1 = fmaf(ar[i], sg, t1);
      }
      float qg[16]; unpack8(q20, qg); unpack8(q21, qg+8);
      float t2 = 0.f;
      #pragma unroll
      for (int i = 0; i < 16; i++){
        float xs = fmaf(qg[i], -L2E, kf2[i]);
        float sg = __builtin_amdgcn_rcpf(1.f + __builtin_amdgcn_exp2f(xs));
        t2 = fmaf(ar[i], sg, t2);
      }
      float ex1 = __builtin_amdgcn_exp2f(t1 * L2E);       // max-free: |t|<=sum|attn|
      float ex2 = has2 ? __builtin_amdgcn_exp2f(t2 * L2E) : 0.f;
      ssum += ex1 + ex2;
      float vf[16]; unpack8(v10, vf); unpack8(v11, vf+8);
      float vg[16]; unpack8(v20, vg); unpack8(v21, vg+8);
      #pragma unroll
      for (int i = 0; i < 16; i++)
        acc[i] = fmaf(ex2, vg[i], fmaf(ex1, vf[i], acc[i]));
    }
    ssum += __shfl_xor(ssum, 8); ssum += __shfl_xor(ssum, 16); ssum += __shfl_xor(ssum, 32);
    #pragma unroll
    for (int i = 0; i < 16; i++){
      acc[i] += __shfl_xor(acc[i], 8);
      acc[i] += __shfl_xor(acc[i], 16);
      acc[i] += __shfl_xor(acc[i], 32);
    }
    if (g == 0){
      float inv_s = 1.f / ssum;
      float4* op = (float4*)(out + (size_t)n*FEATS + h*16);
      op[0] = make_float4(acc[0]*inv_s, acc[1]*inv_s, acc[2]*inv_s, acc[3]*inv_s);
      op[1] = make_float4(acc[4]*inv_s, acc[5]*inv_s, acc[6]*inv_s, acc[7]*inv_s);
      op[2] = make_float4(acc[8]*inv_s, acc[9]*inv_s, acc[10]*inv_s, acc[11]*inv_s);
      op[3] = make_float4(acc[12]*inv_s, acc[13]*inv_s, acc[14]*inv_s, acc[15]*inv_s);
    }
  }
}

extern "C" void kernel_launch(void* const* d_in, const int* in_sizes, int n_in,
                              void* d_out, int out_size, void* d_ws, size_t ws_size,
                              hipStream_t stream){
  (void)in_sizes; (void)n_in; (void)out_size; (void)ws_size;
  const float* ftq  = (const float*)d_in[0];
  const float* ftk  = (const float*)d_in[1];
  const int*   srcE = (const int*)d_in[2];
  const int*   dstE = (const int*)d_in[3];
  const float* Wq   = (const float*)d_in[4];
  const float* bq   = (const float*)d_in[5];
  const float* Wk   = (const float*)d_in[6];
  const float* Wv   = (const float*)d_in[7];
  const float* attn = (const float*)d_in[8];
  const float* gq   = (const float*)d_in[9];
  const float* bqn  = (const float*)d_in[10];
  const float* gk   = (const float*)d_in[11];
  const float* bkn  = (const float*)d_in[12];

  char* ws = (char*)d_ws;
  int*   counts  = (int*)(ws + 0);             // CPAD ints [0, 200704)
  int*   cursor  = (int*)(ws + 200704);        // 50000 ints [200704, 400704)
  float* sums    = (float*)(ws + 400704);      // 512 f [400704, 402752)
  int*   csums   = (int*)(ws + 402752);        // 196 ints [402752, 403536) <- memset end
  int*   offsets = (int*)(ws + 403536);        // CPAD ints (global exclusive offsets)
  int*   src_csr = (int*)(ws + 604240);        // 800000 ints
  unsigned short* Wb = (unsigned short*)(ws + 3804240);  // 3*128*128 bf16
  float* biasf   = (float*)(ws + 3902544);     // 384 f
  unsigned short* qv = (unsigned short*)(ws + 3904080);  // 50000*256 bf16 (q|v interleaved)
  unsigned short* kb = qv + (size_t)N_NODES*256;         // 50000*128 bf16
  float* out = (float*)d_out;

  hipMemsetAsync(ws, 0, 403536, stream);  // counts, cursor, sums, csums

  hipLaunchKernelGGL(stats_hist_kernel, dim3(1024), dim3(256), 0, stream,
                     ftq, ftk, sums, dstE, counts, csums);
  hipLaunchKernelGGL(scan_fold_kernel, dim3(NCHUNK + 96), dim3(256), 0, stream,
                     counts, csums, offsets,
                     Wq, bq, Wk, Wv, gq, bqn, gk, bkn, sums, Wb, biasf);
  hipLaunchKernelGGL(gemm_scatter_kernel, dim3(GEMM_BLOCKS + SCAT_BLOCKS), dim3(256), 0, stream,
                     ftq, ftk, Wb, biasf, qv, kb, dstE, srcE, offsets, cursor, src_csr);
  hipLaunchKernelGGL(node_fused_kernel, dim3(NF_WAVES/4), dim3(256), 0, stream,
                     qv, kb, attn, src_csr, offsets, out);
}